// Round 2
// baseline (2396.273 us; speedup 1.0000x reference)
//
#include <hip/hip_runtime.h>

#define BB 4096
#define TT 64
#define NI 60
#define NH 60
#define NG 180    // 3H
#define NC 600
#define KF 7680   // T * 2H

__device__ __forceinline__ float sigf(float v)     { return 1.f / (1.f + __expf(-v)); }
__device__ __forceinline__ float tanhfast(float v) { return 2.f / (1.f + __expf(-2.f * v)) - 1.f; }

// Recurrence: block = 32 rows x 16 unit-groups (512 thr, 8 waves), one dir.
// Lane (row = tid&31, g = tid>>5) owns units j = 4g..4g+3 (g==15 -> clamped junk,
// write-masked). x[60] and h[60] live in registers per lane (constant-indexed,
// refreshed once/step from LDS); weights stream from LDS as 2-distinct-addr b128.
__global__ __launch_bounds__(512, 2) void gru2_kernel(
    const float* __restrict__ x,      // [B][T][NI]
    const float* __restrict__ w_ih,   // [2][NG][NI]
    const float* __restrict__ w_hh,   // [2][NG][NH]
    const float* __restrict__ b_ih,   // [2][NG]
    const float* __restrict__ b_hh,   // [2][NG]
    float* __restrict__ hs)           // [B][KF]  k = t*120 + d*60 + j
{
    __shared__ float Wi[NG * NI];     // 43.2 KB
    __shared__ float Wh[NG * NH];     // 43.2 KB
    __shared__ float hbuf[32][NH];    // 7.7 KB
    __shared__ float xs[2][2048];     // 16 KB (tid-linear, [row][60] view)

    const int tid = threadIdx.x;
    const int d  = blockIdx.y;
    const int b0 = blockIdx.x * 32;

    // stage weights once
    for (int f = tid; f < (NG * NI) / 4; f += 512) {
        ((float4*)Wi)[f] = ((const float4*)(w_ih + d * NG * NI))[f];
        ((float4*)Wh)[f] = ((const float4*)(w_hh + d * NG * NH))[f];
    }

    const int row = tid & 31;
    const int g   = tid >> 5;            // 0..15
    const bool wvalid = (g < 15);

    int ju[4];
#pragma unroll
    for (int i = 0; i < 4; ++i) { const int j = 4 * g + i; ju[i] = (j < NH) ? j : (NH - 1); }

    float bir[4], biz[4], binn[4], bhr[4], bhz[4], bhn[4];
#pragma unroll
    for (int i = 0; i < 4; ++i) {
        const int j = ju[i];
        bir[i]  = b_ih[d * NG + j];
        biz[i]  = b_ih[d * NG + 60 + j];
        binn[i] = b_ih[d * NG + 120 + j];
        bhr[i]  = b_hh[d * NG + j];
        bhz[i]  = b_hh[d * NG + 60 + j];
        bhn[i]  = b_hh[d * NG + 120 + j];
    }

    // cooperative x-stage / hs-store mapping: tid -> (rowx, cx), 480 active, rest clamped dup
    int rowx = tid / 15, cx = tid - rowx * 15;
    if (tid >= 480) { rowx = 31; cx = 14; }
    const float* xrow_base = x + (size_t)(b0 + rowx) * TT * NI + cx * 4;
    float* hsrow_base = hs + (size_t)(b0 + rowx) * KF + d * 60 + cx * 4;

    // prologue: stage x for step 0
    {
        const int tt0 = d ? (TT - 1) : 0;
        *(float4*)&xs[0][tid * 4] = *(const float4*)(xrow_base + (size_t)tt0 * NI);
    }
    __syncthreads();

    float xr[NI], hr[NH];
#pragma unroll
    for (int q = 0; q < 15; ++q) {
        const float4 v = *(float4*)&xs[0][row * 60 + 4 * q];
        xr[4*q] = v.x; xr[4*q+1] = v.y; xr[4*q+2] = v.z; xr[4*q+3] = v.w;
    }
#pragma unroll
    for (int i = 0; i < NH; ++i) hr[i] = 0.f;
    float hown[4] = {0.f, 0.f, 0.f, 0.f};

#pragma unroll 1
    for (int s = 0; s < TT; ++s) {
        const int tt = d ? (TT - 1 - s) : s;
        const int s1 = s + 1;

        // A: prefetch next step's x (latency hidden under compute)
        float4 xpre = make_float4(0.f, 0.f, 0.f, 0.f);
        if (s1 < TT) {
            const int tt2 = d ? (TT - 1 - s1) : s1;
            xpre = *(const float4*)(xrow_base + (size_t)tt2 * NI);
        }

        // B: 4 units x 3 gates, K=120 (ih merged r/z; hh n-dot kept separate per GRU def)
        float hnew[4];
#pragma unroll
        for (int i = 0; i < 4; ++i) {
            const int j = ju[i];
            const float4* wir = (const float4*)(Wi + (j) * NI);
            const float4* wiz = (const float4*)(Wi + (60 + j) * NI);
            const float4* win = (const float4*)(Wi + (120 + j) * NI);
            const float4* whr = (const float4*)(Wh + (j) * NH);
            const float4* whz = (const float4*)(Wh + (60 + j) * NH);
            const float4* whn = (const float4*)(Wh + (120 + j) * NH);
            float air = 0.f, aiz = 0.f, ain = 0.f, ahr = 0.f, ahz = 0.f, ahn = 0.f;
#pragma unroll
            for (int q = 0; q < 15; ++q) {
                const float4 a = wir[q], b = wiz[q], c = win[q];
                air += a.x*xr[4*q] + a.y*xr[4*q+1] + a.z*xr[4*q+2] + a.w*xr[4*q+3];
                aiz += b.x*xr[4*q] + b.y*xr[4*q+1] + b.z*xr[4*q+2] + b.w*xr[4*q+3];
                ain += c.x*xr[4*q] + c.y*xr[4*q+1] + c.z*xr[4*q+2] + c.w*xr[4*q+3];
            }
#pragma unroll
            for (int q = 0; q < 15; ++q) {
                const float4 a = whr[q], b = whz[q], c = whn[q];
                ahr += a.x*hr[4*q] + a.y*hr[4*q+1] + a.z*hr[4*q+2] + a.w*hr[4*q+3];
                ahz += b.x*hr[4*q] + b.y*hr[4*q+1] + b.z*hr[4*q+2] + b.w*hr[4*q+3];
                ahn += c.x*hr[4*q] + c.y*hr[4*q+1] + c.z*hr[4*q+2] + c.w*hr[4*q+3];
            }
            const float rr = sigf(air + bir[i] + ahr + bhr[i]);
            const float zz = sigf(aiz + biz[i] + ahz + bhz[i]);
            const float nn = tanhfast(ain + binn[i] + rr * (ahn + bhn[i]));
            hnew[i] = (1.f - zz) * nn + zz * hown[i];
            hown[i] = hnew[i];
        }

        // C: publish h' (g==15 lanes masked; their units don't exist)
        if (wvalid)
            *(float4*)&hbuf[row][4 * g] = make_float4(hnew[0], hnew[1], hnew[2], hnew[3]);
        __syncthreads();

        // E: refresh h regs; coalesced hs store; stage prefetched x
#pragma unroll
        for (int q = 0; q < 15; ++q) {
            const float4 v = *(float4*)&hbuf[row][4 * q];
            hr[4*q] = v.x; hr[4*q+1] = v.y; hr[4*q+2] = v.z; hr[4*q+3] = v.w;
        }
        {
            const float4 v = *(float4*)&hbuf[rowx][cx * 4];
            *(float4*)(hsrow_base + (size_t)tt * 120) = v;
        }
        if (s1 < TT) *(float4*)&xs[s1 & 1][tid * 4] = xpre;
        __syncthreads();
        if (s1 < TT) {
#pragma unroll
            for (int q = 0; q < 15; ++q) {
                const float4 v = *(float4*)&xs[s1 & 1][row * 60 + 4 * q];
                xr[4*q] = v.x; xr[4*q+1] = v.y; xr[4*q+2] = v.z; xr[4*q+3] = v.w;
            }
        }
    }
}

// FC: out[b][c] = sum_k hs[b][k] * fcw[c][k] + fcb[c]
// Tile 64 rows x 128 cols, BK=16, 256 thr, thread-tile 4x8, reg-prefetch staging.
__global__ __launch_bounds__(256) void fc2_kernel(
    const float* __restrict__ hs,    // [B][KF]
    const float* __restrict__ fcw,   // [NC][KF]
    const float* __restrict__ fcb,   // [NC]
    float* __restrict__ out)         // [B][NC]
{
    __shared__ float As[16][68];     // [k][b], padded
    __shared__ float Bs[16][132];    // [k][c], padded

    const int tid = threadIdx.x;
    const int tr = tid >> 4;          // 0..15 -> rows tr*4..+3
    const int tc = tid & 15;          // 0..15 -> cols tc*8..+7
    const int b0 = blockIdx.x * 64;
    const int c0 = blockIdx.y * 128;

    // staging maps
    const int abr = tid >> 2, akc = tid & 3;        // A: row abr, k-chunk akc (float4)
    const int bcr = tid >> 1, bkc = tid & 1;        // B: col bcr, k-half bkc (2 float4)
    const float* aptr = hs + (size_t)(b0 + abr) * KF + akc * 4;
    const bool bvalid = (c0 + bcr) < NC;
    const float* bptr = fcw + (size_t)(c0 + (bvalid ? bcr : 0)) * KF + bkc * 8;

    float acc[4][8] = {};

    // stage k0 = 0
    {
        const float4 va = *(const float4*)aptr;
        float4 vb0 = make_float4(0,0,0,0), vb1 = make_float4(0,0,0,0);
        if (bvalid) { vb0 = *(const float4*)bptr; vb1 = *(const float4*)(bptr + 4); }
        As[akc*4+0][abr] = va.x; As[akc*4+1][abr] = va.y; As[akc*4+2][abr] = va.z; As[akc*4+3][abr] = va.w;
        Bs[bkc*8+0][bcr] = vb0.x; Bs[bkc*8+1][bcr] = vb0.y; Bs[bkc*8+2][bcr] = vb0.z; Bs[bkc*8+3][bcr] = vb0.w;
        Bs[bkc*8+4][bcr] = vb1.x; Bs[bkc*8+5][bcr] = vb1.y; Bs[bkc*8+6][bcr] = vb1.z; Bs[bkc*8+7][bcr] = vb1.w;
    }
    __syncthreads();

#pragma unroll 1
    for (int k0 = 0; k0 < KF; k0 += 16) {
        // prefetch next K-tile into regs (latency hidden under compute)
        float4 va = make_float4(0,0,0,0), vb0 = make_float4(0,0,0,0), vb1 = make_float4(0,0,0,0);
        const bool more = (k0 + 16) < KF;
        if (more) {
            va = *(const float4*)(aptr + k0 + 16);
            if (bvalid) { vb0 = *(const float4*)(bptr + k0 + 16); vb1 = *(const float4*)(bptr + k0 + 20); }
        }
#pragma unroll
        for (int k = 0; k < 16; ++k) {
            const float4 a  = *(const float4*)&As[k][tr * 4];
            const float4 w0 = *(const float4*)&Bs[k][tc * 8];
            const float4 w1 = *(const float4*)&Bs[k][tc * 8 + 4];
            const float av[4] = {a.x, a.y, a.z, a.w};
            const float wv[8] = {w0.x, w0.y, w0.z, w0.w, w1.x, w1.y, w1.z, w1.w};
#pragma unroll
            for (int ri = 0; ri < 4; ++ri)
#pragma unroll
                for (int ci = 0; ci < 8; ++ci)
                    acc[ri][ci] += av[ri] * wv[ci];
        }
        __syncthreads();
        if (more) {
            As[akc*4+0][abr] = va.x; As[akc*4+1][abr] = va.y; As[akc*4+2][abr] = va.z; As[akc*4+3][abr] = va.w;
            Bs[bkc*8+0][bcr] = vb0.x; Bs[bkc*8+1][bcr] = vb0.y; Bs[bkc*8+2][bcr] = vb0.z; Bs[bkc*8+3][bcr] = vb0.w;
            Bs[bkc*8+4][bcr] = vb1.x; Bs[bkc*8+5][bcr] = vb1.y; Bs[bkc*8+6][bcr] = vb1.z; Bs[bkc*8+7][bcr] = vb1.w;
        }
        __syncthreads();
    }

    const int c = c0 + tc * 8;
    if (c < NC) {   // NC % 8 == 0, chunks fully in or out
        const float4 bias0 = *(const float4*)&fcb[c];
        const float4 bias1 = *(const float4*)&fcb[c + 4];
#pragma unroll
        for (int ri = 0; ri < 4; ++ri) {
            float* orow = out + (size_t)(b0 + tr * 4 + ri) * NC + c;
            *(float4*)orow       = make_float4(acc[ri][0] + bias0.x, acc[ri][1] + bias0.y,
                                               acc[ri][2] + bias0.z, acc[ri][3] + bias0.w);
            *(float4*)(orow + 4) = make_float4(acc[ri][4] + bias1.x, acc[ri][5] + bias1.y,
                                               acc[ri][6] + bias1.z, acc[ri][7] + bias1.w);
        }
    }
}

extern "C" void kernel_launch(void* const* d_in, const int* in_sizes, int n_in,
                              void* d_out, int out_size, void* d_ws, size_t ws_size,
                              hipStream_t stream) {
    (void)in_sizes; (void)n_in; (void)out_size;
    const float* x    = (const float*)d_in[0];
    const float* w_ih = (const float*)d_in[1];
    const float* w_hh = (const float*)d_in[2];
    const float* b_ih = (const float*)d_in[3];
    const float* b_hh = (const float*)d_in[4];
    const float* fcw  = (const float*)d_in[5];
    const float* fcb  = (const float*)d_in[6];
    float* out = (float*)d_out;
    float* hs  = (float*)d_ws;                        // [B][KF] fp32 = 125.8 MB

    if (ws_size < (size_t)KF * BB * sizeof(float)) return;

    gru2_kernel<<<dim3(BB / 32, 2), 512, 0, stream>>>(x, w_ih, w_hh, b_ih, b_hh, hs);
    fc2_kernel<<<dim3(BB / 64, (NC + 127) / 128), 256, 0, stream>>>(hs, fcw, fcb, out);
}

// Round 3
// 379.686 us; speedup vs baseline: 6.3112x; 6.3112x over previous
//
#include <hip/hip_runtime.h>

#define BB 4096
#define TT 64
#define NH 60
#define KF 7680   // T * 2H
#define NC 600

typedef short bf16x8 __attribute__((ext_vector_type(8)));
typedef float f32x4 __attribute__((ext_vector_type(4)));
#define MFMA16(A,B,C) __builtin_amdgcn_mfma_f32_16x16x32_bf16(A,B,C,0,0,0)

__device__ __forceinline__ unsigned short f2bf(float v) {
    unsigned int u = __float_as_uint(v);
    return (unsigned short)((u + 0x7FFFu + ((u >> 16) & 1u)) >> 16);   // RNE fp32->bf16
}
__device__ __forceinline__ float bf2f(unsigned short b) {
    return __uint_as_float(((unsigned int)b) << 16);
}
__device__ __forceinline__ float sigf(float v)     { return 1.f / (1.f + __expf(-v)); }
__device__ __forceinline__ float tanhfast(float v) { return 2.f / (1.f + __expf(-2.f * v)) - 1.f; }

// ---------------------------------------------------------------------------
// GRU: block = 32 batch rows x 1 direction; 512 thr = 8 waves (2 mtiles x 4 ugroups).
// Per step: D[32][192] = XH[32][128] x W[128][192] via 16x16x32 bf16 MFMA,
// 3-term hi/lo split. W frags live in VGPRs (built once from global fp32).
// XH (x | h) lives in LDS as bf16 hi/lo, XOR-swizzled (16B chunks).
// K layout: x at k=0..59 (pad->63), h at k=64..123 (pad->127).
// N layout: r at n=0..63, z at 64..127, n-gate at 128..191 (j<60 valid).
// n-gate uses split accumulators: kt 0,1 (x side) vs kt 2,3 (h side).
// ---------------------------------------------------------------------------
__global__ __launch_bounds__(512, 2) void gru3_kernel(
    const float* __restrict__ x,      // [B][T][60]
    const float* __restrict__ w_ih,   // [2][180][60]
    const float* __restrict__ w_hh,   // [2][180][60]
    const float* __restrict__ b_ih,   // [2][180]
    const float* __restrict__ b_hh,   // [2][180]
    unsigned int* __restrict__ hs)    // [B][KF] packed (hi<<16 | lo) bf16
{
    __shared__ unsigned short XHh[32 * 128];
    __shared__ unsigned short XHl[32 * 128];
    __shared__ unsigned int hstage[32][60];

    const int tid = threadIdx.x;
    const int d  = blockIdx.y;
    const int b0 = blockIdx.x * 32;
    const int wave = tid >> 6, lane = tid & 63;
    const int mtile = wave >> 2, ug = wave & 3;
    const int l15 = lane & 15, lq = lane >> 4;
    const int j = ug * 16 + l15;          // gate unit owned by this lane (col)
    const bool jv = j < NH;
    const int m = mtile * 16 + l15;       // A-frag row (batch row within block)
    const int rbase = mtile * 16 + lq * 4;// C rows base

    // zero LDS (pads must be 0; h init = 0)
    for (int i = tid; i < 32 * 128; i += 512) { XHh[i] = 0; XHl[i] = 0; }

    // ---- build W frags in registers (hi/lo) ----
    bf16x8 wHf[3][4], wLf[3][4];          // [gate][ktile], fully unrolled access only
#pragma unroll
    for (int g = 0; g < 3; ++g) {
#pragma unroll
        for (int kt = 0; kt < 4; ++kt) {
            bf16x8 h8, l8;
            const int kb = kt * 32 + lq * 8;
#pragma unroll
            for (int e = 0; e < 8; ++e) {
                const int k = kb + e;
                float v = 0.f;
                if (jv) {
                    if (k < 60)                    v = w_ih[(size_t)d * 10800 + (g * 60 + j) * 60 + k];
                    else if (k >= 64 && k < 124)   v = w_hh[(size_t)d * 10800 + (g * 60 + j) * 60 + (k - 64)];
                }
                const unsigned short hb = f2bf(v);
                const unsigned short lb = f2bf(v - bf2f(hb));
                h8[e] = (short)hb; l8[e] = (short)lb;
            }
            wHf[g][kt] = h8; wLf[g][kt] = l8;
        }
    }

    float bir = 0, biz = 0, bin = 0, bhr = 0, bhz = 0, bhn = 0;
    if (jv) {
        bir = b_ih[d * 180 + j]; biz = b_ih[d * 180 + 60 + j]; bin = b_ih[d * 180 + 120 + j];
        bhr = b_hh[d * 180 + j]; bhz = b_hh[d * 180 + 60 + j]; bhn = b_hh[d * 180 + 120 + j];
    }

    // cooperative x-stage / hs-store mapping (480 active threads: 32 rows x 15 float4)
    const bool xact = tid < 480;
    const int rowx = xact ? tid / 15 : 31;
    const int cx   = xact ? tid % 15 : 14;
    const float* xb = x + ((size_t)(b0 + rowx) * TT) * 60 + cx * 4;
    unsigned int* hsb = hs + (size_t)(b0 + rowx) * KF + d * 60 + cx * 4;

    __syncthreads();   // zeroing complete before x staging

    // stage x for step 0
    if (xact) {
        const int tt0 = d ? (TT - 1) : 0;
        const float4 v = *(const float4*)(xb + tt0 * 60);
        const float vv[4] = {v.x, v.y, v.z, v.w};
#pragma unroll
        for (int e = 0; e < 4; ++e) {
            const int k = cx * 4 + e;
            const int idx = rowx * 128 + (((k >> 3) ^ (rowx & 7)) << 3) + (k & 7);
            const unsigned short hb = f2bf(vv[e]);
            XHh[idx] = hb; XHl[idx] = f2bf(vv[e] - bf2f(hb));
        }
    }
    float hold[4] = {0.f, 0.f, 0.f, 0.f};
    __syncthreads();

    for (int s = 0; s < TT; ++s) {
        const int tt = d ? (TT - 1 - s) : s;
        // prefetch next step's x (latency hidden under MFMA phase)
        float4 xp = make_float4(0.f, 0.f, 0.f, 0.f);
        const bool morex = (s < TT - 1) && xact;
        if (morex) xp = *(const float4*)(xb + (d ? (TT - 2 - s) : (s + 1)) * 60);

        // ---- MFMA phase ----
        f32x4 aR = {0,0,0,0}, aZ = {0,0,0,0}, aNX = {0,0,0,0}, aNH = {0,0,0,0};
#pragma unroll
        for (int kt = 0; kt < 4; ++kt) {
            const int c = kt * 4 + lq;
            const int off = m * 128 + ((c ^ (m & 7)) << 3);
            const bf16x8 aH = *(const bf16x8*)(XHh + off);
            const bf16x8 aL = *(const bf16x8*)(XHl + off);
            aR = MFMA16(aH, wHf[0][kt], aR); aR = MFMA16(aH, wLf[0][kt], aR); aR = MFMA16(aL, wHf[0][kt], aR);
            aZ = MFMA16(aH, wHf[1][kt], aZ); aZ = MFMA16(aH, wLf[1][kt], aZ); aZ = MFMA16(aL, wHf[1][kt], aZ);
            if (kt < 2) {
                aNX = MFMA16(aH, wHf[2][kt], aNX); aNX = MFMA16(aH, wLf[2][kt], aNX); aNX = MFMA16(aL, wHf[2][kt], aNX);
            } else {
                aNH = MFMA16(aH, wHf[2][kt], aNH); aNH = MFMA16(aH, wLf[2][kt], aNH); aNH = MFMA16(aL, wHf[2][kt], aNH);
            }
        }

        // ---- gate nonlinearities (lane-local; C layout: col=lane&15, row=lq*4+reg) ----
        float hnew[4];
#pragma unroll
        for (int r = 0; r < 4; ++r) {
            const float rr = sigf(aR[r] + bir + bhr);
            const float zz = sigf(aZ[r] + biz + bhz);
            const float nn = tanhfast(aNX[r] + bin + rr * (aNH[r] + bhn));
            hnew[r] = (1.f - zz) * nn + zz * hold[r];
            hold[r] = hnew[r];
        }
        __syncthreads();   // A: all XH reads of step s complete

        // ---- write h' (hi/lo) + hstage; stage prefetched x for s+1 ----
        if (jv) {
#pragma unroll
            for (int r = 0; r < 4; ++r) {
                const int rw = rbase + r;
                const int k = 64 + j;
                const int idx = rw * 128 + (((k >> 3) ^ (rw & 7)) << 3) + (k & 7);
                const unsigned short hb = f2bf(hnew[r]);
                const unsigned short lb = f2bf(hnew[r] - bf2f(hb));
                XHh[idx] = hb; XHl[idx] = lb;
                hstage[rw][j] = ((unsigned int)hb << 16) | lb;
            }
        }
        if (morex) {
            const float vv[4] = {xp.x, xp.y, xp.z, xp.w};
#pragma unroll
            for (int e = 0; e < 4; ++e) {
                const int k = cx * 4 + e;
                const int idx = rowx * 128 + (((k >> 3) ^ (rowx & 7)) << 3) + (k & 7);
                const unsigned short hb = f2bf(vv[e]);
                XHh[idx] = hb; XHl[idx] = f2bf(vv[e] - bf2f(hb));
            }
        }
        __syncthreads();   // B: writes visible

        // coalesced packed-h store (reads hstage; safe until next barrier A)
        if (xact) {
            const uint4 hv = *(const uint4*)&hstage[rowx][cx * 4];
            *(uint4*)(hsb + (size_t)tt * 120) = hv;
        }
    }
}

// out[b][c] = fcb[c]  (bias init; FC adds atomically on top)
__global__ void out_init_kernel(const float* __restrict__ fcb, float* __restrict__ out) {
    const int i = blockIdx.x * 1024 + threadIdx.x;   // grid exactly covers 4096*600
    out[i] = fcb[i % NC];
}

// ---------------------------------------------------------------------------
// FC: out += hs * fcw^T, split-bf16 3-term MFMA.
// Block tile 256(M) x 128(N), BK=64, K chunked 3x (2560 each), 512 thr = 8 waves
// (4m x 2n, wave-tile 64x64). A from packed hs (unpack at stage), B from fp32
// fcw (cvt at stage). Epilogue: atomicAdd into bias-initialized out.
// ---------------------------------------------------------------------------
__global__ __launch_bounds__(512, 2) void fc3_kernel(
    const unsigned int* __restrict__ hs,  // [B][KF] packed
    const float* __restrict__ fcw,        // [600][KF]
    float* __restrict__ out)              // [B][600]
{
    __shared__ unsigned short AH[256 * 64], AL[256 * 64];   // 32 KB each
    __shared__ unsigned short BH[128 * 64], BL[128 * 64];   // 16 KB each

    const int tid = threadIdx.x;
    const int m0 = blockIdx.x * 256;
    const int n0 = blockIdx.y * 128;
    const int k0 = blockIdx.z * 2560;
    const int wave = tid >> 6, lane = tid & 63;
    const int wm = wave >> 1, wn = wave & 1;
    const int l15 = lane & 15, lq = lane >> 4;

    f32x4 acc[4][4];
#pragma unroll
    for (int a = 0; a < 4; ++a)
#pragma unroll
        for (int b = 0; b < 4; ++b) acc[a][b] = (f32x4){0, 0, 0, 0};

    uint4 pa[8]; float4 pb[4];
    // prime stage for ks = 0
#pragma unroll
    for (int it = 0; it < 8; ++it) {
        const int u = tid + it * 512, row = u >> 4, q = u & 15;
        pa[it] = *(const uint4*)(hs + (size_t)(m0 + row) * KF + k0 + q * 4);
    }
#pragma unroll
    for (int it = 0; it < 4; ++it) {
        const int u = tid + it * 512, row = u >> 4, q = u & 15;
        const int cc = n0 + row;
        pb[it] = (cc < NC) ? *(const float4*)(fcw + (size_t)cc * KF + k0 + q * 4)
                           : make_float4(0.f, 0.f, 0.f, 0.f);
    }

    for (int ks = 0; ks < 40; ++ks) {
        // ---- write staged regs -> LDS (swizzled) ----
#pragma unroll
        for (int it = 0; it < 8; ++it) {
            const int u = tid + it * 512, row = u >> 4, q = u & 15;
            const int off = row * 64 + (((q >> 1) ^ (row & 7)) << 3) + (q & 1) * 4;
            const unsigned int av[4] = {pa[it].x, pa[it].y, pa[it].z, pa[it].w};
            uint2 wh, wl;
            wh.x = (av[0] >> 16) | (av[1] & 0xFFFF0000u);
            wh.y = (av[2] >> 16) | (av[3] & 0xFFFF0000u);
            wl.x = (av[0] & 0xFFFFu) | (av[1] << 16);
            wl.y = (av[2] & 0xFFFFu) | (av[3] << 16);
            *(uint2*)(AH + off) = wh;
            *(uint2*)(AL + off) = wl;
        }
#pragma unroll
        for (int it = 0; it < 4; ++it) {
            const int u = tid + it * 512, row = u >> 4, q = u & 15;
            const int off = row * 64 + (((q >> 1) ^ (row & 7)) << 3) + (q & 1) * 4;
            const float bv[4] = {pb[it].x, pb[it].y, pb[it].z, pb[it].w};
            unsigned short h4[4], l4[4];
#pragma unroll
            for (int e = 0; e < 4; ++e) {
                h4[e] = f2bf(bv[e]);
                l4[e] = f2bf(bv[e] - bf2f(h4[e]));
            }
            uint2 wh, wl;
            wh.x = (unsigned int)h4[0] | ((unsigned int)h4[1] << 16);
            wh.y = (unsigned int)h4[2] | ((unsigned int)h4[3] << 16);
            wl.x = (unsigned int)l4[0] | ((unsigned int)l4[1] << 16);
            wl.y = (unsigned int)l4[2] | ((unsigned int)l4[3] << 16);
            *(uint2*)(BH + off) = wh;
            *(uint2*)(BL + off) = wl;
        }
        __syncthreads();   // staged tile visible

        // ---- prefetch next tile into regs ----
        if (ks + 1 < 40) {
            const int kk = k0 + (ks + 1) * 64;
#pragma unroll
            for (int it = 0; it < 8; ++it) {
                const int u = tid + it * 512, row = u >> 4, q = u & 15;
                pa[it] = *(const uint4*)(hs + (size_t)(m0 + row) * KF + kk + q * 4);
            }
#pragma unroll
            for (int it = 0; it < 4; ++it) {
                const int u = tid + it * 512, row = u >> 4, q = u & 15;
                const int cc = n0 + row;
                pb[it] = (cc < NC) ? *(const float4*)(fcw + (size_t)cc * KF + kk + q * 4)
                                   : make_float4(0.f, 0.f, 0.f, 0.f);
            }
        }

        // ---- MFMA on current tile ----
#pragma unroll
        for (int kt = 0; kt < 2; ++kt) {
            bf16x8 aH[4], aL[4], bH[4], bL[4];
            const int ca = kt * 4 + lq;
#pragma unroll
            for (int t = 0; t < 4; ++t) {
                const int mr = wm * 64 + t * 16 + l15;
                const int offa = mr * 64 + ((ca ^ (mr & 7)) << 3);
                aH[t] = *(const bf16x8*)(AH + offa);
                aL[t] = *(const bf16x8*)(AL + offa);
                const int nr = wn * 64 + t * 16 + l15;
                const int offb = nr * 64 + ((ca ^ (nr & 7)) << 3);
                bH[t] = *(const bf16x8*)(BH + offb);
                bL[t] = *(const bf16x8*)(BL + offb);
            }
#pragma unroll
            for (int mt = 0; mt < 4; ++mt)
#pragma unroll
                for (int nt = 0; nt < 4; ++nt) {
                    acc[mt][nt] = MFMA16(aH[mt], bH[nt], acc[mt][nt]);
                    acc[mt][nt] = MFMA16(aH[mt], bL[nt], acc[mt][nt]);
                    acc[mt][nt] = MFMA16(aL[mt], bH[nt], acc[mt][nt]);
                }
        }
        __syncthreads();   // all reads done; next iter may overwrite
    }

    // ---- epilogue: atomic accumulate (3 k-chunks per out element) ----
#pragma unroll
    for (int mt = 0; mt < 4; ++mt) {
        const int row = m0 + wm * 64 + mt * 16 + lq * 4;
#pragma unroll
        for (int nt = 0; nt < 4; ++nt) {
            const int col = n0 + wn * 64 + nt * 16 + l15;
            if (col < NC) {
#pragma unroll
                for (int r = 0; r < 4; ++r)
                    atomicAdd(out + (size_t)(row + r) * NC + col, acc[mt][nt][r]);
            }
        }
    }
}

extern "C" void kernel_launch(void* const* d_in, const int* in_sizes, int n_in,
                              void* d_out, int out_size, void* d_ws, size_t ws_size,
                              hipStream_t stream) {
    (void)in_sizes; (void)n_in; (void)out_size;
    const float* x    = (const float*)d_in[0];
    const float* w_ih = (const float*)d_in[1];
    const float* w_hh = (const float*)d_in[2];
    const float* b_ih = (const float*)d_in[3];
    const float* b_hh = (const float*)d_in[4];
    const float* fcw  = (const float*)d_in[5];
    const float* fcb  = (const float*)d_in[6];
    float* out = (float*)d_out;
    unsigned int* hs = (unsigned int*)d_ws;          // [B][KF] packed bf16 hi/lo = 125.8 MB

    if (ws_size < (size_t)KF * BB * sizeof(unsigned int)) return;

    out_init_kernel<<<dim3((BB * NC) / 1024), 1024, 0, stream>>>(fcb, out);
    gru3_kernel<<<dim3(BB / 32, 2), 512, 0, stream>>>(x, w_ih, w_hh, b_ih, b_hh, hs);
    fc3_kernel<<<dim3(BB / 256, 5, 3), 512, 0, stream>>>(hs, fcw, out);
}

// Round 4
// 365.600 us; speedup vs baseline: 6.5544x; 1.0385x over previous
//
#include <hip/hip_runtime.h>

#define BB 4096
#define TT 64
#define NH 60
#define KF 7680   // T * 2H
#define NC 600

typedef short bf16x8 __attribute__((ext_vector_type(8)));
typedef float f32x4 __attribute__((ext_vector_type(4)));
#define MFMA16(A,B,C) __builtin_amdgcn_mfma_f32_16x16x32_bf16(A,B,C,0,0,0)

__device__ __forceinline__ unsigned short f2bf(float v) {
    unsigned int u = __float_as_uint(v);
    return (unsigned short)((u + 0x7FFFu + ((u >> 16) & 1u)) >> 16);   // RNE fp32->bf16
}
__device__ __forceinline__ float bf2f(unsigned short b) {
    return __uint_as_float(((unsigned int)b) << 16);
}
__device__ __forceinline__ float sigf(float v)     { return 1.f / (1.f + __expf(-v)); }
__device__ __forceinline__ float tanhfast(float v) { return 2.f / (1.f + __expf(-2.f * v)) - 1.f; }

// ---------------------------------------------------------------------------
// GRU: block = 32 rows x 1 dir; 512 thr = 8 waves (2 mtiles x 4 ugroups).
// Round-4 changes vs gru3: XH + hstage double-buffered -> ONE barrier per step;
// accumulator chains split 6-way (6 dependent MFMAs each instead of 12).
// ---------------------------------------------------------------------------
__global__ __launch_bounds__(512, 2) void gru4_kernel(
    const float* __restrict__ x,      // [B][T][60]
    const float* __restrict__ w_ih,   // [2][180][60]
    const float* __restrict__ w_hh,   // [2][180][60]
    const float* __restrict__ b_ih,   // [2][180]
    const float* __restrict__ b_hh,   // [2][180]
    unsigned int* __restrict__ hs)    // [B][KF] packed (hi<<16 | lo) bf16
{
    __shared__ unsigned short XHh[2][32 * 128];   // 16 KB
    __shared__ unsigned short XHl[2][32 * 128];   // 16 KB
    __shared__ unsigned int hstage[2][32][60];    // 15.4 KB

    const int tid = threadIdx.x;
    const int d  = blockIdx.y;
    const int b0 = blockIdx.x * 32;
    const int wave = tid >> 6, lane = tid & 63;
    const int mtile = wave >> 2, ug = wave & 3;
    const int l15 = lane & 15, lq = lane >> 4;
    const int j = ug * 16 + l15;
    const bool jv = j < NH;
    const int m = mtile * 16 + l15;
    const int rbase = mtile * 16 + lq * 4;

    // zero both buffers (pads must stay 0; h(0) = 0)
    for (int i = tid; i < 2 * 32 * 128; i += 512) { (&XHh[0][0])[i] = 0; (&XHl[0][0])[i] = 0; }

    // ---- build W frags in registers (hi/lo), one-time ----
    bf16x8 wHf[3][4], wLf[3][4];
#pragma unroll
    for (int g = 0; g < 3; ++g) {
#pragma unroll
        for (int kt = 0; kt < 4; ++kt) {
            bf16x8 h8, l8;
            const int kb = kt * 32 + lq * 8;
#pragma unroll
            for (int e = 0; e < 8; ++e) {
                const int k = kb + e;
                float v = 0.f;
                if (jv) {
                    if (k < 60)                    v = w_ih[(size_t)d * 10800 + (g * 60 + j) * 60 + k];
                    else if (k >= 64 && k < 124)   v = w_hh[(size_t)d * 10800 + (g * 60 + j) * 60 + (k - 64)];
                }
                const unsigned short hb = f2bf(v);
                const unsigned short lb = f2bf(v - bf2f(hb));
                h8[e] = (short)hb; l8[e] = (short)lb;
            }
            wHf[g][kt] = h8; wLf[g][kt] = l8;
        }
    }

    float bir = 0, biz = 0, bin = 0, bhr = 0, bhz = 0, bhn = 0;
    if (jv) {
        bir = b_ih[d * 180 + j]; biz = b_ih[d * 180 + 60 + j]; bin = b_ih[d * 180 + 120 + j];
        bhr = b_hh[d * 180 + j]; bhz = b_hh[d * 180 + 60 + j]; bhn = b_hh[d * 180 + 120 + j];
    }

    // cooperative x-stage / hs-store map: 480 active (32 rows x 15 float4)
    const bool xact = tid < 480;
    const int rowx = xact ? tid / 15 : 31;
    const int cx   = xact ? tid % 15 : 14;
    const float* xb = x + ((size_t)(b0 + rowx) * TT) * 60 + cx * 4;
    unsigned int* hsb = hs + (size_t)(b0 + rowx) * KF + d * 60 + cx * 4;

    __syncthreads();   // zeroing complete

    // stage x for step 0 into buf 0
    if (xact) {
        const int tt0 = d ? (TT - 1) : 0;
        const float4 v = *(const float4*)(xb + tt0 * 60);
        const float vv[4] = {v.x, v.y, v.z, v.w};
#pragma unroll
        for (int e = 0; e < 4; ++e) {
            const int k = cx * 4 + e;
            const int idx = rowx * 128 + (((k >> 3) ^ (rowx & 7)) << 3) + (k & 7);
            const unsigned short hb = f2bf(vv[e]);
            XHh[0][idx] = hb; XHl[0][idx] = f2bf(vv[e] - bf2f(hb));
        }
    }
    float hold[4] = {0.f, 0.f, 0.f, 0.f};
    __syncthreads();

#pragma unroll 2
    for (int s = 0; s < TT; ++s) {
        const int p = s & 1, pn = p ^ 1;
        const int tt = d ? (TT - 1 - s) : s;

        // prefetch next step's x (covered by MFMA phase)
        float4 xp = make_float4(0.f, 0.f, 0.f, 0.f);
        const bool morex = (s < TT - 1) && xact;
        if (morex) xp = *(const float4*)(xb + (d ? (TT - 2 - s) : (s + 1)) * 60);

        // ---- MFMA phase on buf p: 6 independent chains of 6 ----
        f32x4 aR0 = {0,0,0,0}, aR1 = {0,0,0,0}, aZ0 = {0,0,0,0}, aZ1 = {0,0,0,0},
              aNX = {0,0,0,0}, aNH_ = {0,0,0,0};
        const unsigned short* Xh = &XHh[p][0];
        const unsigned short* Xl = &XHl[p][0];
#pragma unroll
        for (int kt = 0; kt < 4; ++kt) {
            const int c = kt * 4 + lq;
            const int off = m * 128 + ((c ^ (m & 7)) << 3);
            const bf16x8 aH = *(const bf16x8*)(Xh + off);
            const bf16x8 aL = *(const bf16x8*)(Xl + off);
            if (kt < 2) {
                aR0 = MFMA16(aH, wHf[0][kt], aR0); aR0 = MFMA16(aH, wLf[0][kt], aR0); aR0 = MFMA16(aL, wHf[0][kt], aR0);
                aZ0 = MFMA16(aH, wHf[1][kt], aZ0); aZ0 = MFMA16(aH, wLf[1][kt], aZ0); aZ0 = MFMA16(aL, wHf[1][kt], aZ0);
                aNX = MFMA16(aH, wHf[2][kt], aNX); aNX = MFMA16(aH, wLf[2][kt], aNX); aNX = MFMA16(aL, wHf[2][kt], aNX);
            } else {
                aR1 = MFMA16(aH, wHf[0][kt], aR1); aR1 = MFMA16(aH, wLf[0][kt], aR1); aR1 = MFMA16(aL, wHf[0][kt], aR1);
                aZ1 = MFMA16(aH, wHf[1][kt], aZ1); aZ1 = MFMA16(aH, wLf[1][kt], aZ1); aZ1 = MFMA16(aL, wHf[1][kt], aZ1);
                aNH_ = MFMA16(aH, wHf[2][kt], aNH_); aNH_ = MFMA16(aH, wLf[2][kt], aNH_); aNH_ = MFMA16(aL, wHf[2][kt], aNH_);
            }
        }

        // ---- gates ----
        float hnew[4];
#pragma unroll
        for (int r = 0; r < 4; ++r) {
            const float rr = sigf(aR0[r] + aR1[r] + bir + bhr);
            const float zz = sigf(aZ0[r] + aZ1[r] + biz + bhz);
            const float nn = tanhfast(aNX[r] + bin + rr * (aNH_[r] + bhn));
            hnew[r] = (1.f - zz) * nn + zz * hold[r];
            hold[r] = hnew[r];
        }

        // ---- write h' and x(s+1) into buf pn; hstage[pn] ----
        if (jv) {
#pragma unroll
            for (int r = 0; r < 4; ++r) {
                const int rw = rbase + r;
                const int k = 64 + j;
                const int idx = rw * 128 + (((k >> 3) ^ (rw & 7)) << 3) + (k & 7);
                const unsigned short hb = f2bf(hnew[r]);
                const unsigned short lb = f2bf(hnew[r] - bf2f(hb));
                XHh[pn][idx] = hb; XHl[pn][idx] = lb;
                hstage[pn][rw][j] = ((unsigned int)hb << 16) | lb;
            }
        }
        if (morex) {
            const float vv[4] = {xp.x, xp.y, xp.z, xp.w};
#pragma unroll
            for (int e = 0; e < 4; ++e) {
                const int k = cx * 4 + e;
                const int idx = rowx * 128 + (((k >> 3) ^ (rowx & 7)) << 3) + (k & 7);
                const unsigned short hb = f2bf(vv[e]);
                XHh[pn][idx] = hb; XHl[pn][idx] = f2bf(vv[e] - bf2f(hb));
            }
        }
        __syncthreads();   // the only barrier per step

        // coalesced packed-h store (hstage[pn] safe until barrier of step s+1)
        if (xact) {
            const uint4 hv = *(const uint4*)&hstage[pn][rowx][cx * 4];
            *(uint4*)(hsb + (size_t)tt * 120) = hv;
        }
    }
}

// out[b][c] = fcb[c]  (bias init; FC atomically accumulates on top)
__global__ void out_init_kernel(const float* __restrict__ fcb, float* __restrict__ out) {
    const int i = blockIdx.x * 1024 + threadIdx.x;
    out[i] = fcb[i % NC];
}

// ---------------------------------------------------------------------------
// FC: out += hs * fcw^T, split-bf16 3-term MFMA.
// Round-4: BK=32, DOUBLE-BUFFERED LDS (96 KB), hi/lo merged per 64-short row
// (8-chunk XOR swizzle -> 2-way free), one raw barrier per iter (lgkmcnt only;
// global prefetch stays in flight across it). 256M x 128N, kz=3, 240 blocks.
// ---------------------------------------------------------------------------
__global__ __launch_bounds__(512, 2) void fc4_kernel(
    const unsigned int* __restrict__ hs,  // [B][KF] packed
    const float* __restrict__ fcw,        // [600][KF]
    float* __restrict__ out)              // [B][600]
{
    __shared__ unsigned short Ash[2][256 * 64];   // 32 KB per buf (hi: chunks 0-3, lo: 4-7)
    __shared__ unsigned short Bsh[2][128 * 64];   // 16 KB per buf

    const int tid = threadIdx.x;
    const int m0 = blockIdx.x * 256;
    const int n0 = blockIdx.y * 128;
    const int k0 = blockIdx.z * 2560;
    const int wave = tid >> 6, lane = tid & 63;
    const int wm = wave >> 1, wn = wave & 1;       // 4m x 2n waves, wave-tile 64x64
    const int l15 = lane & 15, lq = lane >> 4;

    f32x4 acc[4][4];
#pragma unroll
    for (int a = 0; a < 4; ++a)
#pragma unroll
        for (int b = 0; b < 4; ++b) acc[a][b] = (f32x4){0, 0, 0, 0};

    uint4 pa[4]; float4 pb[2];

#define STAGE_LOAD(t) do {                                                          \
    const int kc_ = k0 + (t) * 32;                                                  \
    _Pragma("unroll")                                                               \
    for (int it = 0; it < 4; ++it) {                                                \
        const int g_ = tid + it * 512, row_ = g_ >> 3, qi_ = g_ & 7;                \
        pa[it] = *(const uint4*)(hs + (size_t)(m0 + row_) * KF + kc_ + qi_ * 4);    \
    }                                                                               \
    _Pragma("unroll")                                                               \
    for (int it = 0; it < 2; ++it) {                                                \
        const int g_ = tid + it * 512, row_ = g_ >> 3, qi_ = g_ & 7;                \
        const int cc_ = n0 + row_;                                                  \
        pb[it] = (cc_ < NC) ? *(const float4*)(fcw + (size_t)cc_ * KF + kc_ + qi_ * 4) \
                            : make_float4(0.f, 0.f, 0.f, 0.f);                      \
    }                                                                               \
} while (0)

#define STAGE_WRITE(buf) do {                                                       \
    _Pragma("unroll")                                                               \
    for (int it = 0; it < 4; ++it) {                                                \
        const int g_ = tid + it * 512, row_ = g_ >> 3, qi_ = g_ & 7;                \
        const int ch_ = qi_ >> 1, hf_ = qi_ & 1;                                    \
        unsigned short* base_ = &Ash[buf][row_ * 64];                               \
        uint2 wh_, wl_;                                                             \
        wh_.x = (pa[it].x >> 16) | (pa[it].y & 0xFFFF0000u);                        \
        wh_.y = (pa[it].z >> 16) | (pa[it].w & 0xFFFF0000u);                        \
        wl_.x = (pa[it].x & 0xFFFFu) | (pa[it].y << 16);                            \
        wl_.y = (pa[it].z & 0xFFFFu) | (pa[it].w << 16);                            \
        *(uint2*)(base_ + ((ch_ ^ (row_ & 7)) << 3) + hf_ * 4) = wh_;               \
        *(uint2*)(base_ + (((ch_ | 4) ^ (row_ & 7)) << 3) + hf_ * 4) = wl_;         \
    }                                                                               \
    _Pragma("unroll")                                                               \
    for (int it = 0; it < 2; ++it) {                                                \
        const int g_ = tid + it * 512, row_ = g_ >> 3, qi_ = g_ & 7;                \
        const int ch_ = qi_ >> 1, hf_ = qi_ & 1;                                    \
        unsigned short* base_ = &Bsh[buf][row_ * 64];                               \
        const float bv_[4] = {pb[it].x, pb[it].y, pb[it].z, pb[it].w};              \
        unsigned short h4_[4], l4_[4];                                              \
        _Pragma("unroll")                                                           \
        for (int e = 0; e < 4; ++e) { h4_[e] = f2bf(bv_[e]); l4_[e] = f2bf(bv_[e] - bf2f(h4_[e])); } \
        uint2 wh_, wl_;                                                             \
        wh_.x = (unsigned int)h4_[0] | ((unsigned int)h4_[1] << 16);                \
        wh_.y = (unsigned int)h4_[2] | ((unsigned int)h4_[3] << 16);                \
        wl_.x = (unsigned int)l4_[0] | ((unsigned int)l4_[1] << 16);                \
        wl_.y = (unsigned int)l4_[2] | ((unsigned int)l4_[3] << 16);                \
        *(uint2*)(base_ + ((ch_ ^ (row_ & 7)) << 3) + hf_ * 4) = wh_;               \
        *(uint2*)(base_ + (((ch_ | 4) ^ (row_ & 7)) << 3) + hf_ * 4) = wl_;         \
    }                                                                               \
} while (0)

#define MFMA_PHASE(buf) do {                                                        \
    const unsigned short* Ab_ = &Ash[buf][0];                                       \
    const unsigned short* Bb_ = &Bsh[buf][0];                                       \
    bf16x8 aH_[4], aL_[4], bH_[4], bL_[4];                                          \
    _Pragma("unroll")                                                               \
    for (int t = 0; t < 4; ++t) {                                                   \
        const int mr_ = wm * 64 + t * 16 + l15;                                     \
        const unsigned short* p_ = Ab_ + mr_ * 64;                                  \
        aH_[t] = *(const bf16x8*)(p_ + ((lq ^ (mr_ & 7)) << 3));                    \
        aL_[t] = *(const bf16x8*)(p_ + (((lq | 4) ^ (mr_ & 7)) << 3));              \
        const int nr_ = wn * 64 + t * 16 + l15;                                     \
        const unsigned short* q_ = Bb_ + nr_ * 64;                                  \
        bH_[t] = *(const bf16x8*)(q_ + ((lq ^ (nr_ & 7)) << 3));                    \
        bL_[t] = *(const bf16x8*)(q_ + (((lq | 4) ^ (nr_ & 7)) << 3));              \
    }                                                                               \
    _Pragma("unroll")                                                               \
    for (int mt = 0; mt < 4; ++mt)                                                  \
        _Pragma("unroll")                                                           \
        for (int nt = 0; nt < 4; ++nt) {                                            \
            acc[mt][nt] = MFMA16(aH_[mt], bH_[nt], acc[mt][nt]);                    \
            acc[mt][nt] = MFMA16(aH_[mt], bL_[nt], acc[mt][nt]);                    \
            acc[mt][nt] = MFMA16(aL_[mt], bH_[nt], acc[mt][nt]);                    \
        }                                                                           \
} while (0)

#define BARRIER_LGKM() do {                                                         \
    asm volatile("s_waitcnt lgkmcnt(0)" ::: "memory");                              \
    __builtin_amdgcn_s_barrier();                                                   \
    __builtin_amdgcn_sched_barrier(0);                                              \
} while (0)

    // prologue: tile 0 -> buf0; tile 1 -> regs
    STAGE_LOAD(0);
    STAGE_WRITE(0);
    STAGE_LOAD(1);
    __syncthreads();

#pragma unroll 1
    for (int t = 0; t < 80; t += 2) {
        // even half: compute buf0, stage tile t+1 -> buf1, load tile t+2
        STAGE_WRITE(1);                       // t+1 <= 79 always here
        if (t + 2 < 80) STAGE_LOAD(t + 2);
        MFMA_PHASE(0);
        BARRIER_LGKM();
        // odd half: compute buf1, stage tile t+2 -> buf0, load tile t+3
        if (t + 2 < 80) STAGE_WRITE(0);
        if (t + 3 < 80) STAGE_LOAD(t + 3);
        MFMA_PHASE(1);
        BARRIER_LGKM();
    }

    // epilogue: atomic accumulate (3 kz chunks per out element)
#pragma unroll
    for (int mt = 0; mt < 4; ++mt) {
        const int row = m0 + wm * 64 + mt * 16 + lq * 4;
#pragma unroll
        for (int nt = 0; nt < 4; ++nt) {
            const int col = n0 + wn * 64 + nt * 16 + l15;
            if (col < NC) {
#pragma unroll
                for (int r = 0; r < 4; ++r)
                    atomicAdd(out + (size_t)(row + r) * NC + col, acc[mt][nt][r]);
            }
        }
    }
#undef STAGE_LOAD
#undef STAGE_WRITE
#undef MFMA_PHASE
#undef BARRIER_LGKM
}

extern "C" void kernel_launch(void* const* d_in, const int* in_sizes, int n_in,
                              void* d_out, int out_size, void* d_ws, size_t ws_size,
                              hipStream_t stream) {
    (void)in_sizes; (void)n_in; (void)out_size;
    const float* x    = (const float*)d_in[0];
    const float* w_ih = (const float*)d_in[1];
    const float* w_hh = (const float*)d_in[2];
    const float* b_ih = (const float*)d_in[3];
    const float* b_hh = (const float*)d_in[4];
    const float* fcw  = (const float*)d_in[5];
    const float* fcb  = (const float*)d_in[6];
    float* out = (float*)d_out;
    unsigned int* hs = (unsigned int*)d_ws;          // [B][KF] packed bf16 hi/lo = 125.8 MB

    if (ws_size < (size_t)KF * BB * sizeof(unsigned int)) return;

    out_init_kernel<<<dim3((BB * NC) / 1024), 1024, 0, stream>>>(fcb, out);
    gru4_kernel<<<dim3(BB / 32, 2), 512, 0, stream>>>(x, w_ih, w_hh, b_ih, b_hh, hs);
    fc4_kernel<<<dim3(BB / 256, 5, 3), 512, 0, stream>>>(hs, fcw, out);
}